// Round 3
// baseline (54.427 us; speedup 1.0000x reference)
//
#include <hip/hip_runtime.h>

// Median filter 1D, k=9, replicate padding, fp32.
// Input [B=8, C=32, L=131072] flattened: 256 rows of 131072.
// Each thread: 8 outputs (2x float4 nontemporal stores), 4 aligned float4 loads.
// All indexing in 32-bit (total elements = 2^25 < 2^31).

typedef float f32x4 __attribute__((ext_vector_type(4)));  // native vector:
// __builtin_nontemporal_store requires a native vector type, not HIP float4.

#define CE(a, b) do { float _mn = fminf(a, b); (b) = fmaxf(a, b); (a) = _mn; } while (0)

__device__ __forceinline__ float median9(float p0, float p1, float p2,
                                         float p3, float p4, float p5,
                                         float p6, float p7, float p8) {
    // Paeth 19-compare-exchange median-of-9 network; result in p4.
    CE(p1, p2); CE(p4, p5); CE(p7, p8);
    CE(p0, p1); CE(p3, p4); CE(p6, p7);
    CE(p1, p2); CE(p4, p5); CE(p7, p8);
    CE(p0, p3); CE(p5, p8); CE(p4, p7);
    CE(p3, p6); CE(p1, p4); CE(p2, p5);
    CE(p4, p7); CE(p4, p2); CE(p6, p4);
    CE(p4, p2);
    return p4;
}

constexpr int kL         = 131072;            // row length (power of two)
constexpr int kTotal     = 8 * 32 * kL;       // 33,554,432 = 2^25
constexpr int kPerThread = 8;

__global__ __launch_bounds__(256)
void med9_f32_kernel(const float* __restrict__ in, float* __restrict__ out) {
    int t    = blockIdx.x * 256 + threadIdx.x;
    int base = t * kPerThread;                // flattened output index
    int col  = base & (kL - 1);               // position within row
    const float* __restrict__ rin = in + (base - col);

    float v[16];
    if (col >= 4 && col + 12 <= kL) {
        // Interior fast path: 4 aligned 16B loads covering [col-4, col+11].
        f32x4 a = *reinterpret_cast<const f32x4*>(rin + col - 4);
        f32x4 b = *reinterpret_cast<const f32x4*>(rin + col);
        f32x4 c = *reinterpret_cast<const f32x4*>(rin + col + 4);
        f32x4 d = *reinterpret_cast<const f32x4*>(rin + col + 8);
        v[0]  = a.x; v[1]  = a.y; v[2]  = a.z; v[3]  = a.w;
        v[4]  = b.x; v[5]  = b.y; v[6]  = b.z; v[7]  = b.w;
        v[8]  = c.x; v[9]  = c.y; v[10] = c.z; v[11] = c.w;
        v[12] = d.x; v[13] = d.y; v[14] = d.z; v[15] = d.w;
    } else {
        // Row edge: replicate-pad via clamped scalar loads.
#pragma unroll
        for (int j = 0; j < 16; ++j) {
            int idx = col - 4 + j;
            idx = idx < 0 ? 0 : (idx > kL - 1 ? kL - 1 : idx);
            v[j] = rin[idx];
        }
    }

    f32x4 r0, r1;
    r0.x = median9(v[0], v[1], v[2],  v[3],  v[4],  v[5],  v[6],  v[7],  v[8]);
    r0.y = median9(v[1], v[2], v[3],  v[4],  v[5],  v[6],  v[7],  v[8],  v[9]);
    r0.z = median9(v[2], v[3], v[4],  v[5],  v[6],  v[7],  v[8],  v[9],  v[10]);
    r0.w = median9(v[3], v[4], v[5],  v[6],  v[7],  v[8],  v[9],  v[10], v[11]);
    r1.x = median9(v[4], v[5], v[6],  v[7],  v[8],  v[9],  v[10], v[11], v[12]);
    r1.y = median9(v[5], v[6], v[7],  v[8],  v[9],  v[10], v[11], v[12], v[13]);
    r1.z = median9(v[6], v[7], v[8],  v[9],  v[10], v[11], v[12], v[13], v[14]);
    r1.w = median9(v[7], v[8], v[9],  v[10], v[11], v[12], v[13], v[14], v[15]);

    // Nontemporal stores: output is never re-read; don't evict the (reused)
    // input stream from L2.
    __builtin_nontemporal_store(r0, reinterpret_cast<f32x4*>(out + base));
    __builtin_nontemporal_store(r1, reinterpret_cast<f32x4*>(out + base + 4));
}

extern "C" void kernel_launch(void* const* d_in, const int* in_sizes, int n_in,
                              void* d_out, int out_size, void* d_ws, size_t ws_size,
                              hipStream_t stream) {
    const float* x = (const float*)d_in[0];
    // d_in[1] is kernel_size (==9); hardcoded (host can't read device memory
    // during graph capture).
    float* out = (float*)d_out;

    int nthreads = kTotal / kPerThread;       // 4,194,304
    int block = 256;
    int grid = nthreads / block;              // 16,384
    med9_f32_kernel<<<grid, block, 0, stream>>>(x, out);
}

// Round 4
// 46.124 us; speedup vs baseline: 1.1800x; 1.1800x over previous
//
#include <hip/hip_runtime.h>

// Median filter 1D, k=9, replicate padding, fp32.
// Input [B=8, C=32, L=131072] flattened: 256 rows of 131072.
// Each thread: TWO strided 4-output chunks (chunk tid and tid+256 within the
// block) -> 6 independent float4 loads issued up front (2x ILP for latency
// hiding), each load instruction perfectly contiguous across the wave
// (lane stride 16B). Plain stores (nontemporal regressed: bypassing L2 loses
// full-line write aggregation). All indexing 32-bit.

typedef float f32x4 __attribute__((ext_vector_type(4)));

#define CE(a, b) do { float _mn = fminf(a, b); (b) = fmaxf(a, b); (a) = _mn; } while (0)

__device__ __forceinline__ float median9(float p0, float p1, float p2,
                                         float p3, float p4, float p5,
                                         float p6, float p7, float p8) {
    // Paeth 19-compare-exchange median-of-9 network; result in p4.
    CE(p1, p2); CE(p4, p5); CE(p7, p8);
    CE(p0, p1); CE(p3, p4); CE(p6, p7);
    CE(p1, p2); CE(p4, p5); CE(p7, p8);
    CE(p0, p3); CE(p5, p8); CE(p4, p7);
    CE(p3, p6); CE(p1, p4); CE(p2, p5);
    CE(p4, p7); CE(p4, p2); CE(p6, p4);
    CE(p4, p2);
    return p4;
}

constexpr int kL     = 131072;       // row length (power of two)
constexpr int kTotal = 8 * 32 * kL;  // 33,554,432 = 2^25

__device__ __forceinline__ void load12(const float* __restrict__ rin, int col,
                                       float v[12]) {
    if (col >= 4 && col + 8 <= kL) {
        f32x4 a = *reinterpret_cast<const f32x4*>(rin + col - 4);
        f32x4 b = *reinterpret_cast<const f32x4*>(rin + col);
        f32x4 c = *reinterpret_cast<const f32x4*>(rin + col + 4);
        v[0] = a.x; v[1] = a.y; v[2]  = a.z; v[3]  = a.w;
        v[4] = b.x; v[5] = b.y; v[6]  = b.z; v[7]  = b.w;
        v[8] = c.x; v[9] = c.y; v[10] = c.z; v[11] = c.w;
    } else {
#pragma unroll
        for (int j = 0; j < 12; ++j) {
            int idx = col - 4 + j;
            idx = idx < 0 ? 0 : (idx > kL - 1 ? kL - 1 : idx);
            v[j] = rin[idx];
        }
    }
}

__device__ __forceinline__ f32x4 med4(const float v[12]) {
    f32x4 r;
    r.x = median9(v[0], v[1], v[2], v[3], v[4], v[5], v[6],  v[7],  v[8]);
    r.y = median9(v[1], v[2], v[3], v[4], v[5], v[6], v[7],  v[8],  v[9]);
    r.z = median9(v[2], v[3], v[4], v[5], v[6], v[7], v[8],  v[9],  v[10]);
    r.w = median9(v[3], v[4], v[5], v[6], v[7], v[8], v[9],  v[10], v[11]);
    return r;
}

__global__ __launch_bounds__(256)
void med9_f32_kernel(const float* __restrict__ in, float* __restrict__ out) {
    // Each block covers 2048 consecutive floats (within one row: 2048 | kL).
    int base0 = blockIdx.x * 2048 + threadIdx.x * 4;  // chunk 0
    int base1 = base0 + 1024;                         // chunk 1 (tid+256)

    int col0 = base0 & (kL - 1);
    int col1 = col0 + 1024;                           // same row as chunk 0
    const float* __restrict__ rin = in + (base0 - col0);

    // Issue all 6 loads before any compute (independent -> overlapped).
    float v0[12], v1[12];
    load12(rin, col0, v0);
    load12(rin, col1, v1);

    f32x4 r0 = med4(v0);
    f32x4 r1 = med4(v1);

    *reinterpret_cast<f32x4*>(out + base0) = r0;
    *reinterpret_cast<f32x4*>(out + base1) = r1;
}

extern "C" void kernel_launch(void* const* d_in, const int* in_sizes, int n_in,
                              void* d_out, int out_size, void* d_ws, size_t ws_size,
                              hipStream_t stream) {
    const float* x = (const float*)d_in[0];
    // d_in[1] is kernel_size (==9); hardcoded (host can't read device memory
    // during graph capture).
    float* out = (float*)d_out;

    int grid = kTotal / 2048;  // 16,384 blocks x 256 threads x 8 outputs
    med9_f32_kernel<<<grid, 256, 0, stream>>>(x, out);
}

// Round 5
// 44.669 us; speedup vs baseline: 1.2184x; 1.0326x over previous
//
#include <hip/hip_runtime.h>

// Median filter 1D, k=9, replicate padding, fp32.
// Input [B=8, C=32, L=131072] flattened: 256 rows of 131072.
//
// Exact median-of-9 via 3-input min3/med3/max3:
//   split window into 3 disjoint triples, sort each (min3/med3/max3), then
//   median9 = med3( max(lo0,lo1,lo2), med(mi0,mi1,mi2), min(hi0,hi1,hi2) ).
// (Exact: rank-counting proof; NOT the inexact pseudomedian.)
//
// 8 consecutive outputs/thread share sorted triples: outputs t use triples
// starting at t, t+3, t+6 -> only 14 distinct triples per thread.
// 14*3 + 8*4 = 74 VALU ops per 8 outputs (~9/output vs ~47 for the 19-CE
// network), all non-destructive VOP3 (no copy moves), depth 3 vs 13.

typedef float f32x4 __attribute__((ext_vector_type(4)));

__device__ __forceinline__ float min3f(float a, float b, float c) {
    return fminf(fminf(a, b), c);   // fuses to v_min3_f32
}
__device__ __forceinline__ float max3f(float a, float b, float c) {
    return fmaxf(fmaxf(a, b), c);   // fuses to v_max3_f32
}
__device__ __forceinline__ float med3f(float a, float b, float c) {
    return __builtin_amdgcn_fmed3f(a, b, c);
}

constexpr int kL     = 131072;       // row length (power of two)
constexpr int kTotal = 8 * 32 * kL;  // 33,554,432 = 2^25

__global__ __launch_bounds__(256)
void med9_f32_kernel(const float* __restrict__ in, float* __restrict__ out) {
    int base = (blockIdx.x * 256 + threadIdx.x) * 8;  // 8 consecutive outputs
    int col  = base & (kL - 1);
    const float* __restrict__ rin = in + (base - col);

    // v[0..15] = row elements [col-4, col+11]
    float v[16];
    if (col >= 4 && col + 12 <= kL) {
        f32x4 a = *reinterpret_cast<const f32x4*>(rin + col - 4);
        f32x4 b = *reinterpret_cast<const f32x4*>(rin + col);
        f32x4 c = *reinterpret_cast<const f32x4*>(rin + col + 4);
        f32x4 d = *reinterpret_cast<const f32x4*>(rin + col + 8);
        v[0]  = a.x; v[1]  = a.y; v[2]  = a.z; v[3]  = a.w;
        v[4]  = b.x; v[5]  = b.y; v[6]  = b.z; v[7]  = b.w;
        v[8]  = c.x; v[9]  = c.y; v[10] = c.z; v[11] = c.w;
        v[12] = d.x; v[13] = d.y; v[14] = d.z; v[15] = d.w;
    } else {
        // Row edge: replicate-pad via clamped scalar loads (2 threads/row).
#pragma unroll
        for (int j = 0; j < 16; ++j) {
            int idx = col - 4 + j;
            idx = idx < 0 ? 0 : (idx > kL - 1 ? kL - 1 : idx);
            v[j] = rin[idx];
        }
    }

    // Sort the 14 triples v[j..j+2], j = 0..13.
    float lo[14], mi[14], hi[14];
#pragma unroll
    for (int j = 0; j < 14; ++j) {
        lo[j] = min3f(v[j], v[j + 1], v[j + 2]);
        mi[j] = med3f(v[j], v[j + 1], v[j + 2]);
        hi[j] = max3f(v[j], v[j + 1], v[j + 2]);
    }

    // Output t (window v[t..t+8]) = med3 of combined stats of triples t,t+3,t+6.
    float r[8];
#pragma unroll
    for (int t = 0; t < 8; ++t) {
        float P = max3f(lo[t], lo[t + 3], lo[t + 6]);
        float Q = med3f(mi[t], mi[t + 3], mi[t + 6]);
        float R = min3f(hi[t], hi[t + 3], hi[t + 6]);
        r[t] = med3f(P, Q, R);
    }

    f32x4 r0 = { r[0], r[1], r[2], r[3] };
    f32x4 r1 = { r[4], r[5], r[6], r[7] };
    *reinterpret_cast<f32x4*>(out + base)     = r0;
    *reinterpret_cast<f32x4*>(out + base + 4) = r1;
}

extern "C" void kernel_launch(void* const* d_in, const int* in_sizes, int n_in,
                              void* d_out, int out_size, void* d_ws, size_t ws_size,
                              hipStream_t stream) {
    const float* x = (const float*)d_in[0];
    // d_in[1] is kernel_size (==9); hardcoded (host can't read device memory
    // during graph capture).
    float* out = (float*)d_out;

    int grid = kTotal / (256 * 8);  // 16,384 blocks
    med9_f32_kernel<<<grid, 256, 0, stream>>>(x, out);
}